// Round 1
// baseline (10.233 us; speedup 1.0000x reference)
//
#include <hip/hip_runtime.h>

// BPR loss: out = -(1/B) * sum_{b, t < x_len[b]} log_sigmoid(pos - neg) / x_len[b]
// B=32, T=100, N_ITEMS=100000, S=1. Tiny gather-reduction: 6400 scattered
// floats from a 1.28 GB tensor. One block, latency-bound.

#define B_ 32
#define T_ 100
#define N_ 100000
#define S_ 1
#define NTHREADS 1024

__global__ __launch_bounds__(NTHREADS) void bpr_loss_kernel(
    const float* __restrict__ output,
    const int*   __restrict__ labels,
    const int*   __restrict__ x_lens,
    const int*   __restrict__ neg_ids,
    float*       __restrict__ out)
{
    const int tid = threadIdx.x;
    float acc = 0.f;

    for (int i = tid; i < B_ * T_; i += NTHREADS) {
        const int b = i / T_;
        const int t = i - b * T_;
        const int xl = x_lens[b];
        if (t < xl) {
            const int lab = labels[i];
            const float* row = output + (size_t)i * N_;   // row (b,t) of [B,T,N]
            const float pos = row[lab];
            float s = 0.f;
#pragma unroll
            for (int sj = 0; sj < S_; ++sj) {
                const int nid = neg_ids[i * S_ + sj];
                const float neg = row[nid];
                const float x = pos - neg;
                // stable log_sigmoid(x) = min(x,0) - log1p(exp(-|x|))
                s += fminf(x, 0.f) - log1pf(expf(-fabsf(x)));
            }
            acc += s / (float)xl;
        }
    }

    // ---- block reduction (deterministic, no atomics) ----
    // wave-level (64 lanes)
    for (int off = 32; off > 0; off >>= 1)
        acc += __shfl_down(acc, off, 64);

    __shared__ float wsum[NTHREADS / 64];
    const int wid  = tid >> 6;
    const int lane = tid & 63;
    if (lane == 0) wsum[wid] = acc;
    __syncthreads();

    if (wid == 0) {
        float v = (lane < (NTHREADS / 64)) ? wsum[lane] : 0.f;
        for (int off = 8; off > 0; off >>= 1)
            v += __shfl_down(v, off, 64);
        if (lane == 0) out[0] = -v / (float)B_;
    }
}

extern "C" void kernel_launch(void* const* d_in, const int* in_sizes, int n_in,
                              void* d_out, int out_size, void* d_ws, size_t ws_size,
                              hipStream_t stream) {
    const float* output  = (const float*)d_in[0];
    const int*   labels  = (const int*)  d_in[1];
    const int*   x_lens  = (const int*)  d_in[2];
    const int*   neg_ids = (const int*)  d_in[3];
    // d_in[4] = uids, unused by the loss
    float* out = (float*)d_out;

    bpr_loss_kernel<<<1, NTHREADS, 0, stream>>>(output, labels, x_lens, neg_ids, out);
}